// Round 7
// baseline (309.671 us; speedup 1.0000x reference)
//
#include <hip/hip_runtime.h>
#include <hip/hip_bf16.h>

typedef __attribute__((ext_vector_type(8))) short bf16x8;
typedef __attribute__((ext_vector_type(4))) float f32x4;
typedef __hip_bfloat16 bf16;

#define BATCH 8
#define SEQ   2048
#define DMODEL 512
#define DHEAD 64
#define ROWS (BATCH * SEQ)
#define LOG2E 1.44269504f

#define PROJ_BLOCKS (ROWS / 32)          // 512
#define PACK_BLOCKS 1024
#define PACK_NT (PACK_BLOCKS * 512)      // 524288 threads
#define TOT4 (BATCH * SEQ * SEQ / 4)     // 8388608 int4 elements
#define PACK_ITERS (TOT4 / PACK_NT)      // 16

static __device__ inline short f2bf(float f) {
    union { __hip_bfloat16 h; short s; } u;
    u.h = __float2bfloat16(f);
    return u.s;
}

// ---------------------------------------------------------------------------
// W transpose: w[512][64] fp32 -> wt[64][512] bf16, LDS-tiled, coalesced both
// sides. grid (3 sel x 8 k-tiles) = 24 blocks, block 256.
__global__ __launch_bounds__(256) void transpose_w_kernel(
    const float* __restrict__ wq, const float* __restrict__ wk,
    const float* __restrict__ wv, bf16* __restrict__ wt)
{
    const int s  = blockIdx.x / 8;       // 0:wq 1:wk 2:wv
    const int kt = blockIdx.x % 8;       // k-tile of 64
    const float* w = (s == 0) ? wq : ((s == 1) ? wk : wv);

    __shared__ float Ts[64][68];         // [k][n], +4 pad

    const int tid = threadIdx.x;
    int nr = tid >> 4;                   // 0..15
    int n4 = (tid & 15) * 4;
#pragma unroll
    for (int p = 0; p < 4; ++p) {
        int k = 16 * p + nr;
        float4 v = *(const float4*)(w + (size_t)(kt * 64 + k) * DHEAD + n4);
        Ts[k][n4] = v.x; Ts[k][n4 + 1] = v.y; Ts[k][n4 + 2] = v.z; Ts[k][n4 + 3] = v.w;
    }
    __syncthreads();
#pragma unroll
    for (int p = 0; p < 2; ++p) {
        int cc = tid + p * 256;          // 0..511
        int n = cc >> 3;
        int kk = (cc & 7) * 8;
        bf16x8 o;
#pragma unroll
        for (int e = 0; e < 8; ++e) o[e] = f2bf(Ts[kk + e][n]);
        *(bf16x8*)(wt + (size_t)(s * 64 + n) * DMODEL + kt * 64 + kk) = o;
    }
}

// ---------------------------------------------------------------------------
// Fused QKV projection + mask bit-pack (heterogeneous grid).
// Blocks [0, 512): QKV projection.
// Blocks [512, 512+1024): mask pack, structured EXACTLY like the 6.3 TB/s
// grid-stride copy pattern (m13): flat thread id, int4 per lane (1 KB
// contiguous per wave-instruction), grid-stride iterations so the whole
// chip's loads form a dense advancing address front, unroll 4 (~4 KB/wave
// in flight). Ballot per int4 COMPONENT -> 4-way bit-interleaved layout:
//   window W = 256 consecutive ints; word_c (c=0..3) of window W holds
//   bit p = (int at offset 4p+c), stored at mb[4W + c].
// Prior packs (R1: 256B-granule strided; R2: 256B/instr wave-private 4KB
// spans) both hit ~1.1 TB/s — thousands of scattered 256 B-granule DRAM
// streams. This is the page-locality fix.
__global__ __launch_bounds__(512) void proj_pack_kernel(
    const float* __restrict__ x, const bf16* __restrict__ wt,
    const int* __restrict__ mask,
    bf16* __restrict__ Q, bf16* __restrict__ K, bf16* __restrict__ Vt,
    unsigned long long* __restrict__ mb)
{
    if (blockIdx.x >= PROJ_BLOCKS) {
        const int pb = blockIdx.x - PROJ_BLOCKS;
        const int tid = threadIdx.x;
        const int lane = tid & 63;
        const int g = pb * 512 + tid;          // flat thread id
        const int wv = g >> 6;                 // flat wave id
#pragma unroll 4
        for (int it = 0; it < PACK_ITERS; ++it) {
            size_t idx4 = (size_t)g + (size_t)it * PACK_NT;
            int4 v = ((const int4*)mask)[idx4];
            unsigned long long B0 = __ballot(v.x != 0);
            unsigned long long B1 = __ballot(v.y != 0);
            unsigned long long B2 = __ballot(v.z != 0);
            unsigned long long B3 = __ballot(v.w != 0);
            if (lane < 4) {
                // named-scalar select (R4 scratch lesson)
                unsigned long long s01 = (lane & 1) ? B1 : B0;
                unsigned long long s23 = (lane & 1) ? B3 : B2;
                unsigned long long wd  = (lane & 2) ? s23 : s01;
                size_t W = (size_t)wv + (size_t)it * (PACK_NT >> 6);
                mb[4 * W + lane] = wd;
            }
        }
        return;
    }

    // ---- QKV projection ----
    const int r0 = blockIdx.x * 32;
    const int tid = threadIdx.x;
    const int lane = tid & 63;
    const int wid = tid >> 6;          // 0..7
    const int strip = wid & 1;
    const int cq = wid >> 1;           // 0..3
    const int l15 = lane & 15;
    const int quad = lane >> 4;

    f32x4 acc[3] = {};

    const float* xp = x + (size_t)(r0 + 16 * strip + l15) * DMODEL;

    for (int k0 = 0; k0 < DMODEL; k0 += 64) {
        float4 xa = *(const float4*)(xp + k0 + quad * 8);
        float4 xb = *(const float4*)(xp + k0 + quad * 8 + 4);
        float4 xc = *(const float4*)(xp + k0 + 32 + quad * 8);
        float4 xd = *(const float4*)(xp + k0 + 32 + quad * 8 + 4);
        bf16x8 a0, a1;
        a0[0] = f2bf(xa.x); a0[1] = f2bf(xa.y); a0[2] = f2bf(xa.z); a0[3] = f2bf(xa.w);
        a0[4] = f2bf(xb.x); a0[5] = f2bf(xb.y); a0[6] = f2bf(xb.z); a0[7] = f2bf(xb.w);
        a1[0] = f2bf(xc.x); a1[1] = f2bf(xc.y); a1[2] = f2bf(xc.z); a1[3] = f2bf(xc.w);
        a1[4] = f2bf(xd.x); a1[5] = f2bf(xd.y); a1[6] = f2bf(xd.z); a1[7] = f2bf(xd.w);
#pragma unroll
        for (int g = 0; g < 3; ++g) {
            int n = 16 * (3 * cq + g) + l15;
            const bf16* wp = wt + (size_t)n * DMODEL + k0 + quad * 8;
            bf16x8 b0 = *(const bf16x8*)(wp);
            bf16x8 b1 = *(const bf16x8*)(wp + 32);
            acc[g] = __builtin_amdgcn_mfma_f32_16x16x32_bf16(a0, b0, acc[g], 0, 0, 0);
            acc[g] = __builtin_amdgcn_mfma_f32_16x16x32_bf16(a1, b1, acc[g], 0, 0, 0);
        }
    }

#pragma unroll
    for (int g = 0; g < 3; ++g) {
        int ng = 16 * (3 * cq + g) + l15;   // 0..191
        int sel = ng >> 6;
        int col = ng & 63;
#pragma unroll
        for (int r = 0; r < 4; ++r) {
            int row = r0 + 16 * strip + quad * 4 + r;   // flat (b*SEQ + i)
            union { __hip_bfloat16 h; bf16 b; } u;
            u.h = __float2bfloat16(acc[g][r]);
            if (sel == 0)      Q[(size_t)row * DHEAD + col] = u.b;
            else if (sel == 1) K[(size_t)row * DHEAD + col] = u.b;
            else {
                int bb = row >> 11, j = row & (SEQ - 1);
                Vt[((size_t)bb * DHEAD + col) * SEQ + j] = u.b;
            }
        }
    }
}

// ---------------------------------------------------------------------------
// Flash attention with 4-way contiguous j-split, bitmask-fed (R1's proven
// 27 µs structure; only the bit extraction changes for the interleaved pack
// layout).
//
// Consumer algebra: global int index (R, j) -> window W = R*8 + (j>>8),
// offset o = (R*2048+j)&255. With j = wid*512 + kk*64 + 16c + l15:
//   W = R*8 + wid*2 + (kk>>2); word select o&3 = l15&3 (c-independent);
//   bit position o>>2 = (kk&3)*16 + 4c + (l15>>2).
// So per (row, round): one u64 load mq[r*32 + (kk>>2)*4], shift by
// (kk&3)*16 + (l15>>2), needed bits at 0,4,8,12 — all static.
__global__ __launch_bounds__(256) void flash_kernel(
    const bf16* __restrict__ Q, const bf16* __restrict__ K,
    const bf16* __restrict__ Vt, const unsigned long long* __restrict__ mb,
    float* __restrict__ out)
{
    const int b = blockIdx.y;
    const int q0 = blockIdx.x * 16;
    const int tid = threadIdx.x;
    const int lane = tid & 63;
    const int wid = tid >> 6;      // 0..3 = j-split index
    const int l15 = lane & 15;
    const int quad = lane >> 4;

    __shared__ __align__(16) bf16 Ps[4][16][72];    // wave-private P tiles
    __shared__ float Om[4][16][64];                 // partial O per wave
    __shared__ float Mw[4][16];                     // partial m per wave
    __shared__ float Lw[4][16];                     // partial l per wave

    const bf16* qp = Q + ((size_t)(b * SEQ + q0 + l15)) * DHEAD + quad * 8;
    bf16x8 aQ0 = *(const bf16x8*)(qp);
    bf16x8 aQ1 = *(const bf16x8*)(qp + 32);

    f32x4 oacc[4] = {};
    float m_i[4], l_i[4];
#pragma unroll
    for (int r = 0; r < 4; ++r) { m_i[r] = -1e30f; l_i[r] = 0.f; }

    const int jbase = wid * (SEQ / 4);
    // bitmask base for this quad's first row, this wave's j-range
    const unsigned long long* mq =
        mb + (((size_t)(b * SEQ + q0 + quad * 4)) * 8 + wid * 2) * 4 + (l15 & 3);
    const int shl = l15 >> 2;

    for (int kk = 0; kk < 8; ++kk) {
        const int j0 = jbase + kk * 64;

        // mask words for the 4 q-rows (L2-resident, 4 loads)
        unsigned long long mrw[4];
#pragma unroll
        for (int r = 0; r < 4; ++r) mrw[r] = mq[(size_t)r * 32 + (kk >> 2) * 4];

        // S = Q K^T (C layout: row q = quad*4+r, col j = 16c+l15)
        f32x4 sacc[4] = {};
#pragma unroll
        for (int c = 0; c < 4; ++c) {
            const bf16* kp = K + ((size_t)(b * SEQ + j0 + 16 * c + l15)) * DHEAD + quad * 8;
            bf16x8 b0 = *(const bf16x8*)(kp);
            bf16x8 b1 = *(const bf16x8*)(kp + 32);
            sacc[c] = __builtin_amdgcn_mfma_f32_16x16x32_bf16(aQ0, b0, sacc[c], 0, 0, 0);
            sacc[c] = __builtin_amdgcn_mfma_f32_16x16x32_bf16(aQ1, b1, sacc[c], 0, 0, 0);
        }

        // scale + mask: bits at (kk&3)*16 + 4c + (l15>>2) of word (l15&3)
        const int sh = (kk & 3) * 16 + shl;
#pragma unroll
        for (int r = 0; r < 4; ++r) {
            unsigned m = (unsigned)(mrw[r] >> sh);
            sacc[0][r] = (m & 1u)         ? sacc[0][r] * 0.125f : -1e30f;
            sacc[1][r] = ((m >> 4) & 1u)  ? sacc[1][r] * 0.125f : -1e30f;
            sacc[2][r] = ((m >> 8) & 1u)  ? sacc[2][r] * 0.125f : -1e30f;
            sacc[3][r] = ((m >> 12) & 1u) ? sacc[3][r] * 0.125f : -1e30f;
        }

        // online softmax (row r lives on the 16 lanes of this quad)
#pragma unroll
        for (int r = 0; r < 4; ++r) {
            float rm = fmaxf(fmaxf(sacc[0][r], sacc[1][r]), fmaxf(sacc[2][r], sacc[3][r]));
            rm = fmaxf(rm, __shfl_xor(rm, 1));
            rm = fmaxf(rm, __shfl_xor(rm, 2));
            rm = fmaxf(rm, __shfl_xor(rm, 4));
            rm = fmaxf(rm, __shfl_xor(rm, 8));
            float mn = fmaxf(m_i[r], rm);
            float alpha = exp2f((m_i[r] - mn) * LOG2E);
            m_i[r] = mn;
            float rs = 0.f;
#pragma unroll
            for (int c = 0; c < 4; ++c) {
                float pv = exp2f((sacc[c][r] - mn) * LOG2E);
                sacc[c][r] = pv;
                rs += pv;
            }
            rs += __shfl_xor(rs, 1);
            rs += __shfl_xor(rs, 2);
            rs += __shfl_xor(rs, 4);
            rs += __shfl_xor(rs, 8);
            l_i[r] = l_i[r] * alpha + rs;
#pragma unroll
            for (int c = 0; c < 4; ++c) oacc[c][r] *= alpha;
        }

        // P: C-layout -> A-layout via wave-private LDS (no barrier needed)
#pragma unroll
        for (int c = 0; c < 4; ++c)
#pragma unroll
            for (int r = 0; r < 4; ++r) {
                union { __hip_bfloat16 h; bf16 b; } u;
                u.h = __float2bfloat16(sacc[c][r]);
                Ps[wid][quad * 4 + r][16 * c + l15] = u.b;
            }

        bf16x8 aP0 = *(const bf16x8*)(&Ps[wid][l15][quad * 8]);
        bf16x8 aP1 = *(const bf16x8*)(&Ps[wid][l15][32 + quad * 8]);
#pragma unroll
        for (int c = 0; c < 4; ++c) {
            const bf16* vp = Vt + ((size_t)b * DHEAD + 16 * c + l15) * SEQ + j0 + quad * 8;
            bf16x8 v0 = *(const bf16x8*)(vp);
            bf16x8 v1 = *(const bf16x8*)(vp + 32);
            oacc[c] = __builtin_amdgcn_mfma_f32_16x16x32_bf16(aP0, v0, oacc[c], 0, 0, 0);
            oacc[c] = __builtin_amdgcn_mfma_f32_16x16x32_bf16(aP1, v1, oacc[c], 0, 0, 0);
        }
    }

    // stash partials
#pragma unroll
    for (int c = 0; c < 4; ++c)
#pragma unroll
        for (int r = 0; r < 4; ++r)
            Om[wid][quad * 4 + r][16 * c + l15] = oacc[c][r];
    if (l15 == 0) {
#pragma unroll
        for (int r = 0; r < 4; ++r) {
            Mw[wid][quad * 4 + r] = m_i[r];
            Lw[wid][quad * 4 + r] = l_i[r];
        }
    }
    __syncthreads();

    // combine: 256 threads, 4 output floats each (16 rows x 64 cols)
    {
        int row = tid >> 4;
        int c0 = (tid & 15) * 4;
        float M = fmaxf(fmaxf(Mw[0][row], Mw[1][row]), fmaxf(Mw[2][row], Mw[3][row]));
        float sc0 = exp2f((Mw[0][row] - M) * LOG2E);
        float sc1 = exp2f((Mw[1][row] - M) * LOG2E);
        float sc2 = exp2f((Mw[2][row] - M) * LOG2E);
        float sc3 = exp2f((Mw[3][row] - M) * LOG2E);
        float L = Lw[0][row] * sc0 + Lw[1][row] * sc1 + Lw[2][row] * sc2 + Lw[3][row] * sc3;
        float invL = 1.0f / L;
        float4 o;
        float* op = (float*)&o;
#pragma unroll
        for (int e = 0; e < 4; ++e) {
            op[e] = (Om[0][row][c0 + e] * sc0 + Om[1][row][c0 + e] * sc1 +
                     Om[2][row][c0 + e] * sc2 + Om[3][row][c0 + e] * sc3) * invL;
        }
        *(float4*)(out + ((size_t)(b * SEQ + q0 + row)) * DHEAD + c0) = o;
    }
}

extern "C" void kernel_launch(void* const* d_in, const int* in_sizes, int n_in,
                              void* d_out, int out_size, void* d_ws, size_t ws_size,
                              hipStream_t stream)
{
    // setup_inputs order: mask, x_key_value, wk, wq, wv   (wk BEFORE wq!)
    const int*   mask = (const int*)d_in[0];
    const float* x    = (const float*)d_in[1];
    const float* wk   = (const float*)d_in[2];
    const float* wq   = (const float*)d_in[3];
    const float* wv   = (const float*)d_in[4];
    float* out = (float*)d_out;

    bf16* Qb = (bf16*)d_ws;
    bf16* Kb = Qb + (size_t)ROWS * DHEAD;
    bf16* Vt = Kb + (size_t)ROWS * DHEAD;
    bf16* Wt = Vt + (size_t)BATCH * DHEAD * SEQ;
    unsigned long long* Mb = (unsigned long long*)(Wt + 3 * (size_t)DHEAD * DMODEL);

    transpose_w_kernel<<<dim3(24), 256, 0, stream>>>(wq, wk, wv, Wt);
    proj_pack_kernel<<<dim3(PROJ_BLOCKS + PACK_BLOCKS), 512, 0, stream>>>(
        x, Wt, mask, Qb, Kb, Vt, Mb);
    flash_kernel<<<dim3(SEQ / 16, BATCH), 256, 0, stream>>>(Qb, Kb, Vt, Mb, out);
}

// Round 9
// 285.928 us; speedup vs baseline: 1.0830x; 1.0830x over previous
//
#include <hip/hip_runtime.h>
#include <hip/hip_bf16.h>

typedef __attribute__((ext_vector_type(8))) short bf16x8;
typedef __attribute__((ext_vector_type(4))) float f32x4;
typedef __attribute__((ext_vector_type(4))) int i32x4;
typedef __hip_bfloat16 bf16;

#define BATCH 8
#define SEQ   2048
#define DMODEL 512
#define DHEAD 64
#define ROWS (BATCH * SEQ)
#define LOG2E 1.44269504f

static __device__ inline short f2bf(float f) {
    union { __hip_bfloat16 h; short s; } u;
    u.h = __float2bfloat16(f);
    return u.s;
}

// ---------------------------------------------------------------------------
// W transpose: w[512][64] fp32 -> wt[64][512] bf16, LDS-tiled, coalesced both
// sides. grid (3 sel x 8 k-tiles) = 24 blocks, block 256.
__global__ __launch_bounds__(256) void transpose_w_kernel(
    const float* __restrict__ wq, const float* __restrict__ wk,
    const float* __restrict__ wv, bf16* __restrict__ wt)
{
    const int s  = blockIdx.x / 8;       // 0:wq 1:wk 2:wv
    const int kt = blockIdx.x % 8;       // k-tile of 64
    const float* w = (s == 0) ? wq : ((s == 1) ? wk : wv);

    __shared__ float Ts[64][68];         // [k][n], +4 pad

    const int tid = threadIdx.x;
    int nr = tid >> 4;                   // 0..15
    int n4 = (tid & 15) * 4;
#pragma unroll
    for (int p = 0; p < 4; ++p) {
        int k = 16 * p + nr;
        float4 v = *(const float4*)(w + (size_t)(kt * 64 + k) * DHEAD + n4);
        Ts[k][n4] = v.x; Ts[k][n4 + 1] = v.y; Ts[k][n4 + 2] = v.z; Ts[k][n4 + 3] = v.w;
    }
    __syncthreads();
#pragma unroll
    for (int p = 0; p < 2; ++p) {
        int cc = tid + p * 256;          // 0..511
        int n = cc >> 3;
        int kk = (cc & 7) * 8;
        bf16x8 o;
#pragma unroll
        for (int e = 0; e < 8; ++e) o[e] = f2bf(Ts[kk + e][n]);
        *(bf16x8*)(wt + (size_t)(s * 64 + n) * DMODEL + kt * 64 + kk) = o;
    }
}

// ---------------------------------------------------------------------------
// Fused QKV projection. grid ROWS/32 = 512 blocks, block 512 (8 waves).
__global__ __launch_bounds__(512) void proj_kernel(
    const float* __restrict__ x, const bf16* __restrict__ wt,
    bf16* __restrict__ Q, bf16* __restrict__ K, bf16* __restrict__ Vt)
{
    const int r0 = blockIdx.x * 32;
    const int tid = threadIdx.x;
    const int lane = tid & 63;
    const int wid = tid >> 6;          // 0..7
    const int strip = wid & 1;
    const int cq = wid >> 1;           // 0..3
    const int l15 = lane & 15;
    const int quad = lane >> 4;

    f32x4 acc[3] = {};

    const float* xp = x + (size_t)(r0 + 16 * strip + l15) * DMODEL;

    for (int k0 = 0; k0 < DMODEL; k0 += 64) {
        float4 xa = *(const float4*)(xp + k0 + quad * 8);
        float4 xb = *(const float4*)(xp + k0 + quad * 8 + 4);
        float4 xc = *(const float4*)(xp + k0 + 32 + quad * 8);
        float4 xd = *(const float4*)(xp + k0 + 32 + quad * 8 + 4);
        bf16x8 a0, a1;
        a0[0] = f2bf(xa.x); a0[1] = f2bf(xa.y); a0[2] = f2bf(xa.z); a0[3] = f2bf(xa.w);
        a0[4] = f2bf(xb.x); a0[5] = f2bf(xb.y); a0[6] = f2bf(xb.z); a0[7] = f2bf(xb.w);
        a1[0] = f2bf(xc.x); a1[1] = f2bf(xc.y); a1[2] = f2bf(xc.z); a1[3] = f2bf(xc.w);
        a1[4] = f2bf(xd.x); a1[5] = f2bf(xd.y); a1[6] = f2bf(xd.z); a1[7] = f2bf(xd.w);
#pragma unroll
        for (int g = 0; g < 3; ++g) {
            int n = 16 * (3 * cq + g) + l15;
            const bf16* wp = wt + (size_t)n * DMODEL + k0 + quad * 8;
            bf16x8 b0 = *(const bf16x8*)(wp);
            bf16x8 b1 = *(const bf16x8*)(wp + 32);
            acc[g] = __builtin_amdgcn_mfma_f32_16x16x32_bf16(a0, b0, acc[g], 0, 0, 0);
            acc[g] = __builtin_amdgcn_mfma_f32_16x16x32_bf16(a1, b1, acc[g], 0, 0, 0);
        }
    }

#pragma unroll
    for (int g = 0; g < 3; ++g) {
        int ng = 16 * (3 * cq + g) + l15;   // 0..191
        int sel = ng >> 6;
        int col = ng & 63;
#pragma unroll
        for (int r = 0; r < 4; ++r) {
            int row = r0 + 16 * strip + quad * 4 + r;   // flat (b*SEQ + i)
            union { __hip_bfloat16 h; bf16 b; } u;
            u.h = __float2bfloat16(acc[g][r]);
            if (sel == 0)      Q[(size_t)row * DHEAD + col] = u.b;
            else if (sel == 1) K[(size_t)row * DHEAD + col] = u.b;
            else {
                int bb = row >> 11, j = row & (SEQ - 1);
                Vt[((size_t)bb * DHEAD + col) * SEQ + j] = u.b;
            }
        }
    }
}

// ---------------------------------------------------------------------------
// Flash attention, single-pass mask, register-pipelined (R6 structure —
// the measured-best: the ~92 µs capped mask stream overlaps flash's own
// 41 µs compute, so flash = max(stream, compute) ≈ 87 µs, and nothing else
// pays for the mask).
//
// R8 delta: mask i32x4 loads are NON-TEMPORAL (nt flag), via clang
// ext_vector (HIP's int4 struct is not a legal nontemporal operand).
// R7 showed the LLC absorbing ~50 MB of the 134 MB stream; if LLC/L2
// allocation overhead is part of the ~1.5 TB/s input-buffer cap, nt bypass
// helps; if the cap is translation-bound, this is a no-op. Diagnostic
// either way via FETCH_SIZE.
//
// (1) GRANULARITY: 16 B/lane mask loads (4 instrs/round).
// (2) DRAIN ORDER (in-order vmcnt): V hoisted to round top with K, held in
//     regs; PV's wait is counted and leaves next-round mask loads in flight.
//     QK^T's counted kb-wait drains only K + the round-old mask.
// Bit plumbing: ballot_c over component c of group g packs bit (16q+m) =
// mask[row 4g+q][j 4m+c]. Consumer lane (quad,l15), row r, col j=16c+l15:
// word = ballot_{l15&3}(group quad) >> (l15>>2); bit (16r+4c). All selects
// on NAMED scalars (R4 scratch lesson).
__global__ __launch_bounds__(256) void flash_kernel(
    const bf16* __restrict__ Q, const bf16* __restrict__ K,
    const bf16* __restrict__ Vt, const int* __restrict__ mask,
    float* __restrict__ out)
{
    const int b = blockIdx.y;
    const int q0 = blockIdx.x * 16;
    const int tid = threadIdx.x;
    const int lane = tid & 63;
    const int wid = tid >> 6;      // 0..3 = j-split index
    const int l15 = lane & 15;
    const int quad = lane >> 4;

    __shared__ __align__(16) bf16 Ps[4][16][72];    // wave-private P tiles
    __shared__ float Om[4][16][64];                 // partial O per wave
    __shared__ float Mw[4][16];                     // partial m per wave
    __shared__ float Lw[4][16];                     // partial l per wave

    const bf16* qp = Q + ((size_t)(b * SEQ + q0 + l15)) * DHEAD + quad * 8;
    bf16x8 aQ0 = *(const bf16x8*)(qp);
    bf16x8 aQ1 = *(const bf16x8*)(qp + 32);

    f32x4 oacc[4] = {};
    float m_i[4], l_i[4];
#pragma unroll
    for (int r = 0; r < 4; ++r) { m_i[r] = -1e30f; l_i[r] = 0.f; }

    const int jbase = wid * (SEQ / 4);
    // per-lane mask base: row (4g+quad), col 4*l15 within this wave's j-range
    const int* mlane = mask + ((size_t)(b * SEQ + q0 + quad)) * SEQ + jbase + 4 * l15;

#define MLDP(g, kkv) ((const i32x4*)(mlane + (size_t)(4 * (g)) * SEQ + (kkv) * 64))

    // prologue: round-0 mask vectors (one exposed latency, once)
    i32x4 mva = __builtin_nontemporal_load(MLDP(0, 0));
    i32x4 mvb = __builtin_nontemporal_load(MLDP(1, 0));
    i32x4 mvc = __builtin_nontemporal_load(MLDP(2, 0));
    i32x4 mvd = __builtin_nontemporal_load(MLDP(3, 0));

    for (int kk = 0; kk < 8; ++kk) {
        const int j0 = jbase + kk * 64;

        // K and V loads FIRST (both L2-resident). V held in regs until PV so
        // PV's wait is counted and does NOT drain the mask loads.
        bf16x8 kb[8], vr[8];
#pragma unroll
        for (int c = 0; c < 4; ++c) {
            const bf16* kp = K + ((size_t)(b * SEQ + j0 + 16 * c + l15)) * DHEAD + quad * 8;
            kb[2 * c]     = *(const bf16x8*)(kp);
            kb[2 * c + 1] = *(const bf16x8*)(kp + 32);
        }
#pragma unroll
        for (int c = 0; c < 4; ++c) {
            const bf16* vp = Vt + ((size_t)b * DHEAD + 16 * c + l15) * SEQ + j0 + quad * 8;
            vr[2 * c]     = *(const bf16x8*)(vp);
            vr[2 * c + 1] = *(const bf16x8*)(vp + 32);
        }
        __builtin_amdgcn_sched_barrier(0);

        // S = Q K^T. The kb-wait here is counted; it also drains the
        // round-old mask vectors (full-round cover).
        f32x4 sacc[4] = {};
#pragma unroll
        for (int c = 0; c < 4; ++c) {
            sacc[c] = __builtin_amdgcn_mfma_f32_16x16x32_bf16(aQ0, kb[2 * c],     sacc[c], 0, 0, 0);
            sacc[c] = __builtin_amdgcn_mfma_f32_16x16x32_bf16(aQ1, kb[2 * c + 1], sacc[c], 0, 0, 0);
        }
        __builtin_amdgcn_sched_barrier(0);

        // ballots (wave-uniform) from the round-old mask vectors
        unsigned long long B00 = __ballot(mva.x != 0), B01 = __ballot(mva.y != 0),
                           B02 = __ballot(mva.z != 0), B03 = __ballot(mva.w != 0);
        unsigned long long B10 = __ballot(mvb.x != 0), B11 = __ballot(mvb.y != 0),
                           B12 = __ballot(mvb.z != 0), B13 = __ballot(mvb.w != 0);
        unsigned long long B20 = __ballot(mvc.x != 0), B21 = __ballot(mvc.y != 0),
                           B22 = __ballot(mvc.z != 0), B23 = __ballot(mvc.w != 0);
        unsigned long long B30 = __ballot(mvd.x != 0), B31 = __ballot(mvd.y != 0),
                           B32 = __ballot(mvd.z != 0), B33 = __ballot(mvd.w != 0);

        // issue NEXT round's mask loads (consumed next iteration; stay in
        // flight through softmax+P+PV thanks to the counted PV wait)
        if (kk < 7) {
            mva = __builtin_nontemporal_load(MLDP(0, kk + 1));
            mvb = __builtin_nontemporal_load(MLDP(1, kk + 1));
            mvc = __builtin_nontemporal_load(MLDP(2, kk + 1));
            mvd = __builtin_nontemporal_load(MLDP(3, kk + 1));
        }
        __builtin_amdgcn_sched_barrier(0);

        // per-lane word select (named scalars only): group by quad, comp by l15&3
        unsigned long long c0g = (quad & 2) ? ((quad & 1) ? B30 : B20) : ((quad & 1) ? B10 : B00);
        unsigned long long c1g = (quad & 2) ? ((quad & 1) ? B31 : B21) : ((quad & 1) ? B11 : B01);
        unsigned long long c2g = (quad & 2) ? ((quad & 1) ? B32 : B22) : ((quad & 1) ? B12 : B02);
        unsigned long long c3g = (quad & 2) ? ((quad & 1) ? B33 : B23) : ((quad & 1) ? B13 : B03);
        unsigned long long s01 = (l15 & 1) ? c1g : c0g;
        unsigned long long s23 = (l15 & 1) ? c3g : c2g;
        unsigned long long wsel = ((l15 & 2) ? s23 : s01) >> (l15 >> 2);
        unsigned wlo = (unsigned)wsel;
        unsigned whi = (unsigned)(wsel >> 32);

        // scale + mask: bit (16r + 4c) of wsel  (r<2 -> lo, r>=2 -> hi)
#pragma unroll
        for (int c = 0; c < 4; ++c) {
            sacc[c][0] = ((wlo >> (4 * c))      & 1u) ? sacc[c][0] * 0.125f : -1e30f;
            sacc[c][1] = ((wlo >> (16 + 4 * c)) & 1u) ? sacc[c][1] * 0.125f : -1e30f;
            sacc[c][2] = ((whi >> (4 * c))      & 1u) ? sacc[c][2] * 0.125f : -1e30f;
            sacc[c][3] = ((whi >> (16 + 4 * c)) & 1u) ? sacc[c][3] * 0.125f : -1e30f;
        }

        // online softmax (row r lives on the 16 lanes of this quad)
#pragma unroll
        for (int r = 0; r < 4; ++r) {
            float rm = fmaxf(fmaxf(sacc[0][r], sacc[1][r]), fmaxf(sacc[2][r], sacc[3][r]));
            rm = fmaxf(rm, __shfl_xor(rm, 1));
            rm = fmaxf(rm, __shfl_xor(rm, 2));
            rm = fmaxf(rm, __shfl_xor(rm, 4));
            rm = fmaxf(rm, __shfl_xor(rm, 8));
            float mn = fmaxf(m_i[r], rm);
            float alpha = exp2f((m_i[r] - mn) * LOG2E);
            m_i[r] = mn;
            float rs = 0.f;
#pragma unroll
            for (int c = 0; c < 4; ++c) {
                float pv = exp2f((sacc[c][r] - mn) * LOG2E);
                sacc[c][r] = pv;
                rs += pv;
            }
            rs += __shfl_xor(rs, 1);
            rs += __shfl_xor(rs, 2);
            rs += __shfl_xor(rs, 4);
            rs += __shfl_xor(rs, 8);
            l_i[r] = l_i[r] * alpha + rs;
#pragma unroll
            for (int c = 0; c < 4; ++c) oacc[c][r] *= alpha;
        }

        // P: C-layout -> A-layout via wave-private LDS (no barrier needed)
#pragma unroll
        for (int c = 0; c < 4; ++c)
#pragma unroll
            for (int r = 0; r < 4; ++r) {
                union { __hip_bfloat16 h; bf16 b; } u;
                u.h = __float2bfloat16(sacc[c][r]);
                Ps[wid][quad * 4 + r][16 * c + l15] = u.b;
            }

        bf16x8 aP0 = *(const bf16x8*)(&Ps[wid][l15][quad * 8]);
        bf16x8 aP1 = *(const bf16x8*)(&Ps[wid][l15][32 + quad * 8]);
#pragma unroll
        for (int c = 0; c < 4; ++c) {
            oacc[c] = __builtin_amdgcn_mfma_f32_16x16x32_bf16(aP0, vr[2 * c],     oacc[c], 0, 0, 0);
            oacc[c] = __builtin_amdgcn_mfma_f32_16x16x32_bf16(aP1, vr[2 * c + 1], oacc[c], 0, 0, 0);
        }
    }
#undef MLDP

    // stash partials
#pragma unroll
    for (int c = 0; c < 4; ++c)
#pragma unroll
        for (int r = 0; r < 4; ++r)
            Om[wid][quad * 4 + r][16 * c + l15] = oacc[c][r];
    if (l15 == 0) {
#pragma unroll
        for (int r = 0; r < 4; ++r) {
            Mw[wid][quad * 4 + r] = m_i[r];
            Lw[wid][quad * 4 + r] = l_i[r];
        }
    }
    __syncthreads();

    // combine: 256 threads, 4 output floats each (16 rows x 64 cols)
    {
        int row = tid >> 4;
        int c0 = (tid & 15) * 4;
        float M = fmaxf(fmaxf(Mw[0][row], Mw[1][row]), fmaxf(Mw[2][row], Mw[3][row]));
        float sc0 = exp2f((Mw[0][row] - M) * LOG2E);
        float sc1 = exp2f((Mw[1][row] - M) * LOG2E);
        float sc2 = exp2f((Mw[2][row] - M) * LOG2E);
        float sc3 = exp2f((Mw[3][row] - M) * LOG2E);
        float L = Lw[0][row] * sc0 + Lw[1][row] * sc1 + Lw[2][row] * sc2 + Lw[3][row] * sc3;
        float invL = 1.0f / L;
        float4 o;
        float* op = (float*)&o;
#pragma unroll
        for (int e = 0; e < 4; ++e) {
            op[e] = (Om[0][row][c0 + e] * sc0 + Om[1][row][c0 + e] * sc1 +
                     Om[2][row][c0 + e] * sc2 + Om[3][row][c0 + e] * sc3) * invL;
        }
        *(float4*)(out + ((size_t)(b * SEQ + q0 + row)) * DHEAD + c0) = o;
    }
}

extern "C" void kernel_launch(void* const* d_in, const int* in_sizes, int n_in,
                              void* d_out, int out_size, void* d_ws, size_t ws_size,
                              hipStream_t stream)
{
    // setup_inputs order: mask, x_key_value, wk, wq, wv   (wk BEFORE wq!)
    const int*   mask = (const int*)d_in[0];
    const float* x    = (const float*)d_in[1];
    const float* wk   = (const float*)d_in[2];
    const float* wq   = (const float*)d_in[3];
    const float* wv   = (const float*)d_in[4];
    float* out = (float*)d_out;

    bf16* Qb = (bf16*)d_ws;
    bf16* Kb = Qb + (size_t)ROWS * DHEAD;
    bf16* Vt = Kb + (size_t)ROWS * DHEAD;
    bf16* Wt = Vt + (size_t)BATCH * DHEAD * SEQ;

    transpose_w_kernel<<<dim3(24), 256, 0, stream>>>(wq, wk, wv, Wt);
    proj_kernel<<<dim3(ROWS / 32), 512, 0, stream>>>(x, Wt, Qb, Kb, Vt);
    flash_kernel<<<dim3(SEQ / 16, BATCH), 256, 0, stream>>>(Qb, Kb, Vt, mask, out);
}